// Round 7
// baseline (519.033 us; speedup 1.0000x reference)
//
#include <hip/hip_runtime.h>

typedef __bf16 bf16x8 __attribute__((ext_vector_type(8)));
typedef float f32x4 __attribute__((ext_vector_type(4)));
typedef unsigned int uint32x4 __attribute__((ext_vector_type(4)));

#define DD 256
#define VV 1024
#define BN 16
#define KC1 36   // extended-K chunks of 8 (288/8): 32 data + c2 + zeros

__device__ __forceinline__ unsigned short f2bf(float f) {
    unsigned int b = __float_as_uint(f);
    b += 0x7FFFu + ((b >> 16) & 1u);
    return (unsigned short)(b >> 16);
}

// Prep: fragment-major codebook layouts.
// cbA[vtile=v/16][kc=0..35][i=v%16][j=0..7]: kc<32 -> cb[v][kc*8+j] bf16;
//   kc=32,j=0 -> hi(-c2/2), kc=32,j=1 -> lo, else 0.
// cbB[dtile=d/16][kc=v/8][i=d%16][j=v%8] = cb[v][d] bf16.
__global__ __launch_bounds__(256) void vq_prep_kernel(
    const float* __restrict__ cb,
    unsigned short* __restrict__ cbA,   // [V/16][KC1][16][8]
    unsigned short* __restrict__ cbB)   // [D/16][128][16][8]
{
    int v = blockIdx.x;
    int t = threadIdx.x;
    float val = cb[(size_t)v * DD + t];
    unsigned short h = f2bf(val);
    const int vtile = v >> 4, vi = v & 15;
    cbA[(((size_t)vtile * KC1 + (t >> 3)) * 16 + vi) * 8 + (t & 7)] = h;
    cbB[(((size_t)(t >> 4) * 128 + (v >> 3)) * 16 + (t & 15)) * 8 + (v & 7)] = h;
    float p = val * val;
#pragma unroll
    for (int d = 1; d < 64; d <<= 1) p += __shfl_xor(p, d);
    __shared__ float ps[4];
    if ((t & 63) == 0) ps[t >> 6] = p;
    __syncthreads();
    if (t < 32) {
        float c2 = ps[0] + ps[1] + ps[2] + ps[3];
        float m = -0.5f * c2;
        unsigned short hi = f2bf(m);
        float hif = __uint_as_float((unsigned int)hi << 16);
        unsigned short lo = f2bf(m - hif);
        unsigned short o = (t == 0) ? hi : ((t == 1) ? lo : (unsigned short)0);
        cbA[(((size_t)vtile * KC1 + 32 + (t >> 3)) * 16 + vi) * 8 + (t & 7)] = o;
    }
}

// accurate-enough -log(u): log1p poly near 1 (relative accuracy where it matters),
// hardware log elsewhere.
__device__ __forceinline__ float neg_log_u(float u) {
    float t = u - 1.0f;  // exact for u in [0.5, 1]
    float p = t * (1.0f + t * (-0.5f + t * (0.33333333f + t * (-0.25f + t * 0.2f))));
    float lg = (u >= 0.984375f) ? p : __logf(u);
    return -lg;
}

// Kernel A: GEMM1 + fused gumbel-softmax -> out_p (exact f32).
// One block = 16 rows, 4 waves each owning a V-chunk of 256.
// Swapped GEMM1 -> lane owns (x-row = lane&15, v = vb+16nt+4*lrow+r).
// LDS = 512 B (softmax combine only); 1 barrier.
__global__ __launch_bounds__(256, 3) void vq_softmax_kernel(
    const float* __restrict__ x,          // [N][D]
    const float* __restrict__ gum,        // [N][V]
    const unsigned short* __restrict__ cbA,
    float* __restrict__ out_p)            // [N][V]
{
    __shared__ float sredA[4][BN];
    __shared__ float sredB[4][BN];

    const int tid  = threadIdx.x;
    const int wave = tid >> 6;
    const int lane = tid & 63;
    const int lrow = lane >> 4;   // 0..3
    const int lcol = lane & 15;   // 0..15
    const int row0 = blockIdx.x * BN;
    const int vb   = wave * 256;  // this wave's V-chunk base

    // ---- Phase 0: x -> B-fragments (afr) in registers + x2 via shuffles ----
    bf16x8 afr[9];
    float x2 = 0.f;
    {
        const float* xrow = x + (size_t)(row0 + lcol) * DD + lrow * 8;
        float4 xa[8], xb[8];
#pragma unroll
        for (int kt = 0; kt < 8; ++kt) {
            xa[kt] = *reinterpret_cast<const float4*>(xrow + kt * 32);
            xb[kt] = *reinterpret_cast<const float4*>(xrow + kt * 32 + 4);
        }
#pragma unroll
        for (int kt = 0; kt < 8; ++kt) {
            float v8[8] = {xa[kt].x, xa[kt].y, xa[kt].z, xa[kt].w,
                           xb[kt].x, xb[kt].y, xb[kt].z, xb[kt].w};
            uint32x4 w;
#pragma unroll
            for (int j = 0; j < 4; ++j) {
                x2 += v8[2 * j] * v8[2 * j] + v8[2 * j + 1] * v8[2 * j + 1];
                w[j] = (unsigned int)f2bf(v8[2 * j]) |
                       ((unsigned int)f2bf(v8[2 * j + 1]) << 16);
            }
            afr[kt] = __builtin_bit_cast(bf16x8, w);
        }
        x2 += __shfl_xor(x2, 16);
        x2 += __shfl_xor(x2, 32);   // x2 of row lcol, replicated
        uint32x4 w = {0u, 0u, 0u, 0u};
        if (lrow == 0) w[0] = 0x3F803F80u;  // two bf16 1.0 at k=256,257
        afr[8] = __builtin_bit_cast(bf16x8, w);
    }

    // gumbel chunk 0 issued early (hidden under GEMM1)
    const float* grow = gum + (size_t)(row0 + lcol) * VV + vb + lrow * 4;
    float4 gcur[4], gnxt[4];
#pragma unroll
    for (int i = 0; i < 4; ++i)
        gcur[i] = *reinterpret_cast<const float4*>(grow + i * 16);

    // ---- GEMM1 (swapped): acc[nt]: v = vb+16nt+4lrow+r, x-row = lcol ----
    f32x4 acc[16];
#pragma unroll
    for (int nt = 0; nt < 16; ++nt) acc[nt] = (f32x4){0.f, 0.f, 0.f, 0.f};

    const int laneoff = lrow * 128 + lcol * 8;
#pragma unroll
    for (int nt = 0; nt < 16; ++nt) {
        const unsigned short* ap =
            cbA + ((size_t)(vb >> 4) + nt) * (KC1 * 128) + laneoff;
#pragma unroll
        for (int kt = 0; kt < 9; ++kt) {
            bf16x8 cfr = __builtin_bit_cast(bf16x8,
                *reinterpret_cast<const uint32x4*>(ap + kt * 512));
            acc[nt] = __builtin_amdgcn_mfma_f32_16x16x32_bf16(cfr, afr[kt], acc[nt], 0, 0, 0);
        }
    }

    // ---- logits + one-pass softmax, gumbel pipelined 4-deep ----
    float mp = -1e30f;
#pragma unroll
    for (int c = 0; c < 4; ++c) {
        if (c < 3) {
#pragma unroll
            for (int i = 0; i < 4; ++i)
                gnxt[i] = *reinterpret_cast<const float4*>(grow + (c * 4 + 4 + i) * 16);
        }
#pragma unroll
        for (int i = 0; i < 4; ++i) {
            const int nt = c * 4 + i;
            float uu[4] = {gcur[i].x, gcur[i].y, gcur[i].z, gcur[i].w};
#pragma unroll
            for (int r = 0; r < 4; ++r) {
                float u = fminf(fmaxf(uu[r], 1e-10f), 1.0f - 1e-10f);
                float w = neg_log_u(u);       // -log(u) > 0
                float g = -__logf(w);         // gumbel
                float d2 = fmaxf(x2 - 2.0f * acc[nt][r], 1e-12f);
                float lg = (g - sqrtf(d2)) * 0.5f;   // TEMP = 2
                acc[nt][r] = lg;
                mp = fmaxf(mp, lg);
            }
        }
#pragma unroll
        for (int i = 0; i < 4; ++i) gcur[i] = gnxt[i];
    }
    mp = fmaxf(mp, __shfl_xor(mp, 16));
    mp = fmaxf(mp, __shfl_xor(mp, 32));   // wave-local row max

    float ss = 0.f;
#pragma unroll
    for (int nt = 0; nt < 16; ++nt) {
#pragma unroll
        for (int r = 0; r < 4; ++r) {
            float e = __expf(acc[nt][r] - mp);
            acc[nt][r] = e;
            ss += e;
        }
    }
    ss += __shfl_xor(ss, 16);
    ss += __shfl_xor(ss, 32);

    if (lane < 16) { sredA[wave][lcol] = mp; sredB[wave][lcol] = ss; }
    __syncthreads();

    // combine across waves: global max m, Z; f = exp(mp - m) / Z
    float m0 = sredA[0][lcol], m1 = sredA[1][lcol];
    float m2 = sredA[2][lcol], m3 = sredA[3][lcol];
    float m = fmaxf(fmaxf(m0, m1), fmaxf(m2, m3));
    float Z = sredB[0][lcol] * __expf(m0 - m) + sredB[1][lcol] * __expf(m1 - m) +
              sredB[2][lcol] * __expf(m2 - m) + sredB[3][lcol] * __expf(m3 - m);
    const float f = __expf(mp - m) / Z;

    // ---- out_p: direct per-lane float4 stores (exact f32, v-contiguous) ----
    {
        float* oprow = out_p + (size_t)(row0 + lcol) * VV + vb + lrow * 4;
#pragma unroll
        for (int nt = 0; nt < 16; ++nt)
            *reinterpret_cast<float4*>(oprow + nt * 16) =
                (float4){acc[nt][0] * f, acc[nt][1] * f, acc[nt][2] * f, acc[nt][3] * f};
    }
}

// Kernel B: out_q[N][256] = prob[N][1024] @ cb[1024][256].
// One block = 64 rows (4 row-groups of 16), 4 waves owning D-chunks of 64.
// A-frags read directly from out_p (f32 -> bf16 in regs); cbB fragment-major,
// each frag reused across the 4 row-groups. No LDS, no barriers.
__global__ __launch_bounds__(256, 4) void vq_gemm2_kernel(
    const float* __restrict__ out_p,      // [N][V]
    const unsigned short* __restrict__ cbB,
    float* __restrict__ out_q)            // [N][D]
{
    const int tid  = threadIdx.x;
    const int wave = tid >> 6;
    const int lane = tid & 63;
    const int lrow = lane >> 4;   // 0..3
    const int lcol = lane & 15;   // 0..15
    const int row0 = blockIdx.x * 64;
    const int dbw  = wave * 64;   // this wave's D-chunk base

    const int laneoff = lrow * 128 + lcol * 8;
    const unsigned short* bb[4];
#pragma unroll
    for (int nt = 0; nt < 4; ++nt)
        bb[nt] = cbB + ((size_t)(dbw >> 4) + nt) * (128 * 128) + laneoff;

    f32x4 q[4][4];
#pragma unroll
    for (int g = 0; g < 4; ++g)
#pragma unroll
        for (int nt = 0; nt < 4; ++nt) q[g][nt] = (f32x4){0.f, 0.f, 0.f, 0.f};

#pragma unroll 4
    for (int kt = 0; kt < 32; ++kt) {
        bf16x8 bfr[4];
#pragma unroll
        for (int nt = 0; nt < 4; ++nt)
            bfr[nt] = __builtin_bit_cast(bf16x8,
                *reinterpret_cast<const uint32x4*>(bb[nt] + kt * 512));
#pragma unroll
        for (int g = 0; g < 4; ++g) {
            const float* pr =
                out_p + (size_t)(row0 + g * 16 + lcol) * VV + kt * 32 + lrow * 8;
            float4 a = *reinterpret_cast<const float4*>(pr);
            float4 b = *reinterpret_cast<const float4*>(pr + 4);
            float v8[8] = {a.x, a.y, a.z, a.w, b.x, b.y, b.z, b.w};
            uint32x4 w;
#pragma unroll
            for (int j = 0; j < 4; ++j)
                w[j] = (unsigned int)f2bf(v8[2 * j]) |
                       ((unsigned int)f2bf(v8[2 * j + 1]) << 16);
            bf16x8 pfr = __builtin_bit_cast(bf16x8, w);
#pragma unroll
            for (int nt = 0; nt < 4; ++nt)
                q[g][nt] = __builtin_amdgcn_mfma_f32_16x16x32_bf16(pfr, bfr[nt], q[g][nt], 0, 0, 0);
        }
    }

    // store: C[row=(g*16)+lrow*4+r][d=dbw+nt*16+lcol]
#pragma unroll
    for (int g = 0; g < 4; ++g) {
        float* qrow0 = out_q + (size_t)(row0 + g * 16 + lrow * 4) * DD + dbw + lcol;
#pragma unroll
        for (int r = 0; r < 4; ++r) {
            float* qr = qrow0 + r * DD;
#pragma unroll
            for (int nt = 0; nt < 4; ++nt) qr[nt * 16] = q[g][nt][r];
        }
    }
}

extern "C" void kernel_launch(void* const* d_in, const int* in_sizes, int n_in,
                              void* d_out, int out_size, void* d_ws, size_t ws_size,
                              hipStream_t stream) {
    (void)in_sizes; (void)n_in; (void)out_size; (void)ws_size;
    const float* x   = (const float*)d_in[0];   // [16,4096,256]
    const float* cb  = (const float*)d_in[1];   // [1024,256]
    const float* gum = (const float*)d_in[2];   // [65536,1024]

    const int N = 16 * 4096;
    float* out_q = (float*)d_out;                       // [N][256]
    float* out_p = out_q + (size_t)N * DD;              // [N][1024]

    unsigned short* cbA = (unsigned short*)d_ws;        // 576 KB fragment-major
    unsigned short* cbB = cbA + (size_t)64 * KC1 * 128; // 512 KB fragment-major
    vq_prep_kernel<<<VV, 256, 0, stream>>>(cb, cbA, cbB);
    vq_softmax_kernel<<<N / BN, 256, 0, stream>>>(x, gum, cbA, out_p);
    vq_gemm2_kernel<<<N / 64, 256, 0, stream>>>(out_p, cbB, out_q);
}

// Round 8
// 515.504 us; speedup vs baseline: 1.0068x; 1.0068x over previous
//
#include <hip/hip_runtime.h>

typedef __bf16 bf16x8 __attribute__((ext_vector_type(8)));
typedef float f32x4 __attribute__((ext_vector_type(4)));
typedef unsigned int uint32x4 __attribute__((ext_vector_type(4)));

#define DD 256
#define VV 1024
#define BN 16
#define KC1 36   // extended-K chunks of 8 (288/8): 32 data + c2 + zeros
#define WVA 8    // waves in kernel A
#define VCH 128  // V-chunk per wave in kernel A

__device__ __forceinline__ unsigned short f2bf(float f) {
    unsigned int b = __float_as_uint(f);
    b += 0x7FFFu + ((b >> 16) & 1u);
    return (unsigned short)(b >> 16);
}

// K-permutation sigma: memory index d -> fragment slot (kc, j).
// Lane (lrow) loads float4 at d = kt*32 + lrow*4 (+16 for j=4..7) => per-instr
// 64B contiguous per row. kc = (d>>5)*4 + ((d>>2)&3), j = (d&3) + ((d>>4)&1)*4.

// Prep: fragment-major, sigma-permuted codebook layouts.
// cbA[vtile][kc=0..35][i=v%16][j]: kc<32 per sigma; kc=32,j=0 -> hi(-c2/2), j=1 -> lo.
// cbB[dtile][kc=0..127 per sigma over v][i=d%16][j].
__global__ __launch_bounds__(256) void vq_prep_kernel(
    const float* __restrict__ cb,
    unsigned short* __restrict__ cbA,   // [V/16][KC1][16][8]
    unsigned short* __restrict__ cbB)   // [D/16][128][16][8]
{
    int v = blockIdx.x;
    int t = threadIdx.x;
    float val = cb[(size_t)v * DD + t];
    unsigned short h = f2bf(val);
    const int vtile = v >> 4, vi = v & 15;
    // cbA: k-dim = t (d), sigma slot
    const int kc_t = (t >> 5) * 4 + ((t >> 2) & 3);
    const int j_t  = (t & 3) + ((t >> 4) & 1) * 4;
    cbA[(((size_t)vtile * KC1 + kc_t) * 16 + vi) * 8 + j_t] = h;
    // cbB: k-dim = v, sigma slot
    const int kcv = (v >> 5) * 4 + ((v >> 2) & 3);
    const int jv  = (v & 3) + ((v >> 4) & 1) * 4;
    cbB[(((size_t)(t >> 4) * 128 + kcv) * 16 + (t & 15)) * 8 + jv] = h;

    float p = val * val;
#pragma unroll
    for (int d = 1; d < 64; d <<= 1) p += __shfl_xor(p, d);
    __shared__ float ps[4];
    if ((t & 63) == 0) ps[t >> 6] = p;
    __syncthreads();
    if (t < 32) {
        float c2 = ps[0] + ps[1] + ps[2] + ps[3];
        float m = -0.5f * c2;
        unsigned short hi = f2bf(m);
        float hif = __uint_as_float((unsigned int)hi << 16);
        unsigned short lo = f2bf(m - hif);
        unsigned short o = (t == 0) ? hi : ((t == 1) ? lo : (unsigned short)0);
        cbA[(((size_t)vtile * KC1 + 32 + (t >> 3)) * 16 + vi) * 8 + (t & 7)] = o;
    }
}

// accurate-enough -log(u): log1p poly near 1 (relative accuracy where it matters),
// hardware log elsewhere.
__device__ __forceinline__ float neg_log_u(float u) {
    float t = u - 1.0f;  // exact for u in [0.5, 1]
    float p = t * (1.0f + t * (-0.5f + t * (0.33333333f + t * (-0.25f + t * 0.2f))));
    float lg = (u >= 0.984375f) ? p : __logf(u);
    return -lg;
}

// Kernel A: GEMM1 + fused gumbel-softmax -> out_p (exact f32).
// One block = 16 rows, 8 waves each owning a V-chunk of 128.
// Lane owns (x-row = lane&15, v = vb+16nt+4*lrow+r). All gumbel loads issue
// before GEMM1 (hidden under 72 MFMAs). LDS = 1 KB; 1 barrier.
__global__ __launch_bounds__(512, 4) void vq_softmax_kernel(
    const float* __restrict__ x,          // [N][D]
    const float* __restrict__ gum,        // [N][V]
    const unsigned short* __restrict__ cbA,
    float* __restrict__ out_p)            // [N][V]
{
    __shared__ float sredA[WVA][BN];
    __shared__ float sredB[WVA][BN];

    const int tid  = threadIdx.x;
    const int wave = tid >> 6;    // 0..7
    const int lane = tid & 63;
    const int lrow = (lane >> 4) & 3;
    const int lcol = lane & 15;
    const int row0 = blockIdx.x * BN;
    const int vb   = wave * VCH;  // this wave's V-chunk base

    // ---- x -> B-fragments (sigma-permuted: 64B/row per instruction) + x2 ----
    bf16x8 afr[9];
    float x2 = 0.f;
    {
        const float* xrow = x + (size_t)(row0 + lcol) * DD + lrow * 4;
        float4 xa[8], xb[8];
#pragma unroll
        for (int kt = 0; kt < 8; ++kt) {
            xa[kt] = *reinterpret_cast<const float4*>(xrow + kt * 32);
            xb[kt] = *reinterpret_cast<const float4*>(xrow + kt * 32 + 16);
        }
#pragma unroll
        for (int kt = 0; kt < 8; ++kt) {
            float v8[8] = {xa[kt].x, xa[kt].y, xa[kt].z, xa[kt].w,
                           xb[kt].x, xb[kt].y, xb[kt].z, xb[kt].w};
            uint32x4 w;
#pragma unroll
            for (int j = 0; j < 4; ++j) {
                x2 += v8[2 * j] * v8[2 * j] + v8[2 * j + 1] * v8[2 * j + 1];
                w[j] = (unsigned int)f2bf(v8[2 * j]) |
                       ((unsigned int)f2bf(v8[2 * j + 1]) << 16);
            }
            afr[kt] = __builtin_bit_cast(bf16x8, w);
        }
        x2 += __shfl_xor(x2, 16);
        x2 += __shfl_xor(x2, 32);   // x2 of row lcol, replicated
        uint32x4 w = {0u, 0u, 0u, 0u};
        if (lrow == 0) w[0] = 0x3F803F80u;  // two bf16 1.0 at c2 slots
        afr[8] = __builtin_bit_cast(bf16x8, w);
    }

    // ---- gumbel: ALL 8 loads issued before GEMM1 (latency hidden by MFMAs) ----
    const float* grow = gum + (size_t)(row0 + lcol) * VV + vb + lrow * 4;
    float4 gu[8];
#pragma unroll
    for (int nt = 0; nt < 8; ++nt)
        gu[nt] = *reinterpret_cast<const float4*>(grow + nt * 16);

    // ---- GEMM1 (swapped): acc[nt]: v = vb+16nt+4lrow+r, x-row = lcol ----
    f32x4 acc[8];
#pragma unroll
    for (int nt = 0; nt < 8; ++nt) acc[nt] = (f32x4){0.f, 0.f, 0.f, 0.f};

    const int laneoff = lrow * 128 + lcol * 8;
#pragma unroll
    for (int nt = 0; nt < 8; ++nt) {
        const unsigned short* ap =
            cbA + ((size_t)(vb >> 4) + nt) * (KC1 * 128) + laneoff;
#pragma unroll
        for (int kt = 0; kt < 9; ++kt) {
            bf16x8 cfr = __builtin_bit_cast(bf16x8,
                *reinterpret_cast<const uint32x4*>(ap + kt * 512));
            acc[nt] = __builtin_amdgcn_mfma_f32_16x16x32_bf16(cfr, afr[kt], acc[nt], 0, 0, 0);
        }
    }

    // ---- logits + one-pass softmax (32 lane-local elements) ----
    float mp = -1e30f;
#pragma unroll
    for (int nt = 0; nt < 8; ++nt) {
        float uu[4] = {gu[nt].x, gu[nt].y, gu[nt].z, gu[nt].w};
#pragma unroll
        for (int r = 0; r < 4; ++r) {
            float u = fminf(fmaxf(uu[r], 1e-10f), 1.0f - 1e-10f);
            float w = neg_log_u(u);       // -log(u) > 0
            float g = -__logf(w);         // gumbel
            float d2 = fmaxf(x2 - 2.0f * acc[nt][r], 1e-12f);
            float lg = (g - sqrtf(d2)) * 0.5f;   // TEMP = 2
            acc[nt][r] = lg;
            mp = fmaxf(mp, lg);
        }
    }
    mp = fmaxf(mp, __shfl_xor(mp, 16));
    mp = fmaxf(mp, __shfl_xor(mp, 32));   // wave-local row max

    float ss = 0.f;
#pragma unroll
    for (int nt = 0; nt < 8; ++nt) {
#pragma unroll
        for (int r = 0; r < 4; ++r) {
            float e = __expf(acc[nt][r] - mp);
            acc[nt][r] = e;
            ss += e;
        }
    }
    ss += __shfl_xor(ss, 16);
    ss += __shfl_xor(ss, 32);

    if (lane < 16) { sredA[wave][lcol] = mp; sredB[wave][lcol] = ss; }
    __syncthreads();

    // combine across 8 waves: global max m, Z; f = exp(mp - m) / Z
    float m = sredA[0][lcol];
#pragma unroll
    for (int w = 1; w < WVA; ++w) m = fmaxf(m, sredA[w][lcol]);
    float Z = 0.f;
#pragma unroll
    for (int w = 0; w < WVA; ++w)
        Z += sredB[w][lcol] * __expf(sredA[w][lcol] - m);
    const float f = __expf(mp - m) / Z;

    // ---- out_p: direct per-lane float4 stores (exact f32, v-contiguous) ----
    {
        float* oprow = out_p + (size_t)(row0 + lcol) * VV + vb + lrow * 4;
#pragma unroll
        for (int nt = 0; nt < 8; ++nt)
            *reinterpret_cast<float4*>(oprow + nt * 16) =
                (float4){acc[nt][0] * f, acc[nt][1] * f, acc[nt][2] * f, acc[nt][3] * f};
    }
}

// Kernel B: out_q[N][256] = prob[N][1024] @ cb[1024][256].
// One block = 32 rows (2 row-groups of 16), 4 waves owning D-chunks of 64.
// Sigma-permuted prob loads (64B/row per instruction); q[2][4] = 32 AGPR.
__global__ __launch_bounds__(256, 4) void vq_gemm2_kernel(
    const float* __restrict__ out_p,      // [N][V]
    const unsigned short* __restrict__ cbB,
    float* __restrict__ out_q)            // [N][D]
{
    const int tid  = threadIdx.x;
    const int wave = tid >> 6;
    const int lane = tid & 63;
    const int lrow = (lane >> 4) & 3;
    const int lcol = lane & 15;
    const int row0 = blockIdx.x * 32;
    const int dbw  = wave * 64;   // this wave's D-chunk base
    const int laneoff = lrow * 128 + lcol * 8;

    const unsigned short* bb =
        cbB + (size_t)(dbw >> 4) * (128 * 128) + laneoff;

    f32x4 q[2][4];
#pragma unroll
    for (int g = 0; g < 2; ++g)
#pragma unroll
        for (int nt = 0; nt < 4; ++nt) q[g][nt] = (f32x4){0.f, 0.f, 0.f, 0.f};

    const float* pr0 = out_p + (size_t)(row0 + lcol) * VV + lrow * 4;
    const float* pr1 = pr0 + (size_t)16 * VV;

#pragma unroll 2
    for (int kt = 0; kt < 32; ++kt) {
        float4 a0 = *reinterpret_cast<const float4*>(pr0 + kt * 32);
        float4 b0 = *reinterpret_cast<const float4*>(pr0 + kt * 32 + 16);
        float4 a1 = *reinterpret_cast<const float4*>(pr1 + kt * 32);
        float4 b1 = *reinterpret_cast<const float4*>(pr1 + kt * 32 + 16);
        bf16x8 bfr[4];
#pragma unroll
        for (int nt = 0; nt < 4; ++nt)
            bfr[nt] = __builtin_bit_cast(bf16x8,
                *reinterpret_cast<const uint32x4*>(bb + nt * 16384 + kt * 512));
        float v80[8] = {a0.x, a0.y, a0.z, a0.w, b0.x, b0.y, b0.z, b0.w};
        float v81[8] = {a1.x, a1.y, a1.z, a1.w, b1.x, b1.y, b1.z, b1.w};
        uint32x4 w0, w1;
#pragma unroll
        for (int j = 0; j < 4; ++j) {
            w0[j] = (unsigned int)f2bf(v80[2 * j]) |
                    ((unsigned int)f2bf(v80[2 * j + 1]) << 16);
            w1[j] = (unsigned int)f2bf(v81[2 * j]) |
                    ((unsigned int)f2bf(v81[2 * j + 1]) << 16);
        }
        bf16x8 pfr0 = __builtin_bit_cast(bf16x8, w0);
        bf16x8 pfr1 = __builtin_bit_cast(bf16x8, w1);
#pragma unroll
        for (int nt = 0; nt < 4; ++nt) {
            q[0][nt] = __builtin_amdgcn_mfma_f32_16x16x32_bf16(pfr0, bfr[nt], q[0][nt], 0, 0, 0);
            q[1][nt] = __builtin_amdgcn_mfma_f32_16x16x32_bf16(pfr1, bfr[nt], q[1][nt], 0, 0, 0);
        }
    }

    // store: C[row = row0 + g*16 + lrow*4 + r][d = dbw + nt*16 + lcol]
#pragma unroll
    for (int g = 0; g < 2; ++g) {
        float* qrow0 = out_q + (size_t)(row0 + g * 16 + lrow * 4) * DD + dbw + lcol;
#pragma unroll
        for (int r = 0; r < 4; ++r) {
            float* qr = qrow0 + r * DD;
#pragma unroll
            for (int nt = 0; nt < 4; ++nt) qr[nt * 16] = q[g][nt][r];
        }
    }
}

extern "C" void kernel_launch(void* const* d_in, const int* in_sizes, int n_in,
                              void* d_out, int out_size, void* d_ws, size_t ws_size,
                              hipStream_t stream) {
    (void)in_sizes; (void)n_in; (void)out_size; (void)ws_size;
    const float* x   = (const float*)d_in[0];   // [16,4096,256]
    const float* cb  = (const float*)d_in[1];   // [1024,256]
    const float* gum = (const float*)d_in[2];   // [65536,1024]

    const int N = 16 * 4096;
    float* out_q = (float*)d_out;                       // [N][256]
    float* out_p = out_q + (size_t)N * DD;              // [N][1024]

    unsigned short* cbA = (unsigned short*)d_ws;        // 576 KB fragment-major
    unsigned short* cbB = cbA + (size_t)64 * KC1 * 128; // 512 KB fragment-major
    vq_prep_kernel<<<VV, 256, 0, stream>>>(cb, cbA, cbB);
    vq_softmax_kernel<<<N / BN, 512, 0, stream>>>(x, gum, cbA, out_p);
    vq_gemm2_kernel<<<N / 32, 256, 0, stream>>>(out_p, cbB, out_q);
}

// Round 9
// 482.228 us; speedup vs baseline: 1.0763x; 1.0690x over previous
//
#include <hip/hip_runtime.h>

typedef __bf16 bf16x8 __attribute__((ext_vector_type(8)));
typedef float f32x4 __attribute__((ext_vector_type(4)));
typedef unsigned int uint32x4 __attribute__((ext_vector_type(4)));

#define DD 256
#define VV 1024
#define BN 16
#define KC1 36   // extended-K chunks of 8 (288/8): 32 data + c2 + zeros
#define WVA 8    // waves in kernel A
#define VCH 128  // V-chunk per wave in kernel A

__device__ __forceinline__ unsigned short f2bf(float f) {
    unsigned int b = __float_as_uint(f);
    b += 0x7FFFu + ((b >> 16) & 1u);
    return (unsigned short)(b >> 16);
}

// async global->LDS, 16B per lane. LDS dst must be WAVE-UNIFORM base
// (HW adds lane*16); global src is per-lane.
typedef __attribute__((address_space(3))) unsigned int lds_uint;
typedef __attribute__((address_space(1))) const unsigned int glb_uint;
__device__ __forceinline__ void dma16(const float* g, float* l) {
    __builtin_amdgcn_global_load_lds((glb_uint*)g, (lds_uint*)l, 16, 0, 0);
}

// Prep: fragment-major, sigma-permuted codebook layouts.
// sigma: element d -> kc = (d>>5)*4 + ((d>>2)&3), j = (d&3) + ((d>>4)&1)*4.
__global__ __launch_bounds__(256) void vq_prep_kernel(
    const float* __restrict__ cb,
    unsigned short* __restrict__ cbA,   // [V/16][KC1][16][8]
    unsigned short* __restrict__ cbB)   // [D/16][128][16][8]
{
    int v = blockIdx.x;
    int t = threadIdx.x;
    float val = cb[(size_t)v * DD + t];
    unsigned short h = f2bf(val);
    const int vtile = v >> 4, vi = v & 15;
    const int kc_t = (t >> 5) * 4 + ((t >> 2) & 3);
    const int j_t  = (t & 3) + ((t >> 4) & 1) * 4;
    cbA[(((size_t)vtile * KC1 + kc_t) * 16 + vi) * 8 + j_t] = h;
    const int kcv = (v >> 5) * 4 + ((v >> 2) & 3);
    const int jv  = (v & 3) + ((v >> 4) & 1) * 4;
    cbB[(((size_t)(t >> 4) * 128 + kcv) * 16 + (t & 15)) * 8 + jv] = h;

    float p = val * val;
#pragma unroll
    for (int d = 1; d < 64; d <<= 1) p += __shfl_xor(p, d);
    __shared__ float ps[4];
    if ((t & 63) == 0) ps[t >> 6] = p;
    __syncthreads();
    if (t < 32) {
        float c2 = ps[0] + ps[1] + ps[2] + ps[3];
        float m = -0.5f * c2;
        unsigned short hi = f2bf(m);
        float hif = __uint_as_float((unsigned int)hi << 16);
        unsigned short lo = f2bf(m - hif);
        unsigned short o = (t == 0) ? hi : ((t == 1) ? lo : (unsigned short)0);
        cbA[(((size_t)vtile * KC1 + 32 + (t >> 3)) * 16 + vi) * 8 + (t & 7)] = o;
    }
}

// accurate-enough -log(u)
__device__ __forceinline__ float neg_log_u(float u) {
    float t = u - 1.0f;
    float p = t * (1.0f + t * (-0.5f + t * (0.33333333f + t * (-0.25f + t * 0.2f))));
    float lg = (u >= 0.984375f) ? p : __logf(u);
    return -lg;
}

// Kernel A: GEMM1 + fused gumbel-softmax -> out_p.
// x and raw gumbel staged to LDS via global_load_lds (dense, no VGPR dst).
// Counted vmcnt + raw s_barrier keep gumbel DMA in flight under GEMM1.
// LDS: xbuf 16 KB (reused for softmax combine) + gbuf 64 KB = 80 KB -> 2 blocks/CU.
__global__ __launch_bounds__(512, 4) void vq_softmax_kernel(
    const float* __restrict__ x,          // [N][D]
    const float* __restrict__ gum,        // [N][V]
    const unsigned short* __restrict__ cbA,
    float* __restrict__ out_p)            // [N][V]
{
    __shared__ __align__(16) float xbuf[BN * DD];   // 16 KB
    __shared__ __align__(16) float gbuf[BN * VV];   // 64 KB

    const int tid  = threadIdx.x;
    const int wave = tid >> 6;    // 0..7
    const int lane = tid & 63;
    const int lrow = (lane >> 4) & 3;
    const int lcol = lane & 15;
    const int row0 = blockIdx.x * BN;
    const int vb   = wave * VCH;

    // ---- DMA issue: x rows (2/wave), then gumbel rows (2/wave x 4 KB) ----
    // LDS layout: linear granules; data placed so LDS granule g holds global
    // granule g ^ (row&7) (16B XOR swizzle, both-sides involution).
#pragma unroll
    for (int h = 0; h < 2; ++h) {
        const int r = wave * 2 + h;
        dma16(x + (size_t)(row0 + r) * DD + (((lane ^ (r & 7)) & 63) << 2),
              &xbuf[r * DD]);
    }
#pragma unroll
    for (int h = 0; h < 2; ++h) {
        const int r = wave * 2 + h;
        const float* gsrc = gum + (size_t)(row0 + r) * VV;
#pragma unroll
        for (int i = 0; i < 4; ++i) {
            const int g = i * 64 + lane;
            dma16(gsrc + ((g ^ (r & 7)) << 2), &gbuf[r * VV + i * 256]);
        }
    }
    // wait x (2 oldest of 10 per wave), leave 8 gumbel DMAs in flight
    asm volatile("s_waitcnt vmcnt(8)" ::: "memory");
    __builtin_amdgcn_sched_barrier(0);
    __builtin_amdgcn_s_barrier();

    // ---- afr from xbuf (sigma slots) + x2 ----
    bf16x8 afr[9];
    float x2 = 0.f;
#pragma unroll
    for (int kt = 0; kt < 8; ++kt) {
        const int g1 = (kt * 8 + lrow) ^ (lcol & 7);
        const int g2 = (kt * 8 + lrow + 4) ^ (lcol & 7);
        f32x4 a = *reinterpret_cast<const f32x4*>(&xbuf[lcol * DD + g1 * 4]);
        f32x4 b = *reinterpret_cast<const f32x4*>(&xbuf[lcol * DD + g2 * 4]);
        float v8[8] = {a[0], a[1], a[2], a[3], b[0], b[1], b[2], b[3]};
        uint32x4 w;
#pragma unroll
        for (int j = 0; j < 4; ++j) {
            x2 += v8[2 * j] * v8[2 * j] + v8[2 * j + 1] * v8[2 * j + 1];
            w[j] = (unsigned int)f2bf(v8[2 * j]) |
                   ((unsigned int)f2bf(v8[2 * j + 1]) << 16);
        }
        afr[kt] = __builtin_bit_cast(bf16x8, w);
    }
    x2 += __shfl_xor(x2, 16);
    x2 += __shfl_xor(x2, 32);   // full-row x2 of row lcol
    {
        uint32x4 w = {0u, 0u, 0u, 0u};
        if (lrow == 0) w[0] = 0x3F803F80u;  // bf16 1.0 pair at c2 slots
        afr[8] = __builtin_bit_cast(bf16x8, w);
    }

    // ---- GEMM1 (swapped): acc[nt]: v = vb+16nt+4lrow+r, x-row = lcol ----
    f32x4 acc[8];
#pragma unroll
    for (int nt = 0; nt < 8; ++nt) acc[nt] = (f32x4){0.f, 0.f, 0.f, 0.f};

    const int laneoff = lrow * 128 + lcol * 8;
#pragma unroll
    for (int nt = 0; nt < 8; ++nt) {
        const unsigned short* ap =
            cbA + ((size_t)(vb >> 4) + nt) * (KC1 * 128) + laneoff;
#pragma unroll
        for (int kt = 0; kt < 9; ++kt) {
            bf16x8 cfr = __builtin_bit_cast(bf16x8,
                *reinterpret_cast<const uint32x4*>(ap + kt * 512));
            acc[nt] = __builtin_amdgcn_mfma_f32_16x16x32_bf16(cfr, afr[kt], acc[nt], 0, 0, 0);
        }
    }

    // gumbel DMA done + all waves past xbuf reads
    asm volatile("s_waitcnt vmcnt(0)" ::: "memory");
    __builtin_amdgcn_sched_barrier(0);
    __builtin_amdgcn_s_barrier();

    // ---- logits + one-pass softmax; gumbel from LDS (zero HBM latency) ----
    float mp = -1e30f;
#pragma unroll
    for (int nt = 0; nt < 8; ++nt) {
        const int gg = ((vb >> 2) + nt * 4 + lrow) ^ (lcol & 7);
        f32x4 u4 = *reinterpret_cast<const f32x4*>(&gbuf[lcol * VV + gg * 4]);
#pragma unroll
        for (int r = 0; r < 4; ++r) {
            float u = fminf(fmaxf(u4[r], 1e-10f), 1.0f - 1e-10f);
            float w = neg_log_u(u);
            float g = -__logf(w);
            float d2 = fmaxf(x2 - 2.0f * acc[nt][r], 1e-12f);
            float lg = (g - sqrtf(d2)) * 0.5f;   // TEMP = 2
            acc[nt][r] = lg;
            mp = fmaxf(mp, lg);
        }
    }
    mp = fmaxf(mp, __shfl_xor(mp, 16));
    mp = fmaxf(mp, __shfl_xor(mp, 32));

    float ss = 0.f;
#pragma unroll
    for (int nt = 0; nt < 8; ++nt) {
#pragma unroll
        for (int r = 0; r < 4; ++r) {
            float e = __expf(acc[nt][r] - mp);
            acc[nt][r] = e;
            ss += e;
        }
    }
    ss += __shfl_xor(ss, 16);
    ss += __shfl_xor(ss, 32);

    // xbuf reused as sred (x consumed by all waves before barrier #2)
    if (lane < 16) {
        xbuf[wave * 16 + lane] = mp;          // sredA
        xbuf[128 + wave * 16 + lane] = ss;    // sredB
    }
    asm volatile("s_waitcnt lgkmcnt(0)" ::: "memory");
    __builtin_amdgcn_s_barrier();

    float mv[WVA], sv[WVA];
#pragma unroll
    for (int w = 0; w < WVA; ++w) {
        mv[w] = xbuf[w * 16 + lcol];
        sv[w] = xbuf[128 + w * 16 + lcol];
    }
    float m = mv[0];
#pragma unroll
    for (int w = 1; w < WVA; ++w) m = fmaxf(m, mv[w]);
    float Z = 0.f;
#pragma unroll
    for (int w = 0; w < WVA; ++w) Z += sv[w] * __expf(mv[w] - m);
    const float f = __expf(mp - m) / Z;

    // ---- out_p: per-lane float4 stores (exact f32, v-contiguous) ----
    {
        float* oprow = out_p + (size_t)(row0 + lcol) * VV + vb + lrow * 4;
#pragma unroll
        for (int nt = 0; nt < 8; ++nt)
            *reinterpret_cast<float4*>(oprow + nt * 16) =
                (float4){acc[nt][0] * f, acc[nt][1] * f, acc[nt][2] * f, acc[nt][3] * f};
    }
}

// Kernel B: out_q = prob @ cb (unchanged from R8).
__global__ __launch_bounds__(256, 4) void vq_gemm2_kernel(
    const float* __restrict__ out_p,      // [N][V]
    const unsigned short* __restrict__ cbB,
    float* __restrict__ out_q)            // [N][D]
{
    const int tid  = threadIdx.x;
    const int wave = tid >> 6;
    const int lane = tid & 63;
    const int lrow = (lane >> 4) & 3;
    const int lcol = lane & 15;
    const int row0 = blockIdx.x * 32;
    const int dbw  = wave * 64;
    const int laneoff = lrow * 128 + lcol * 8;

    const unsigned short* bb =
        cbB + (size_t)(dbw >> 4) * (128 * 128) + laneoff;

    f32x4 q[2][4];
#pragma unroll
    for (int g = 0; g < 2; ++g)
#pragma unroll
        for (int nt = 0; nt < 4; ++nt) q[g][nt] = (f32x4){0.f, 0.f, 0.f, 0.f};

    const float* pr0 = out_p + (size_t)(row0 + lcol) * VV + lrow * 4;
    const float* pr1 = pr0 + (size_t)16 * VV;

#pragma unroll 2
    for (int kt = 0; kt < 32; ++kt) {
        float4 a0 = *reinterpret_cast<const float4*>(pr0 + kt * 32);
        float4 b0 = *reinterpret_cast<const float4*>(pr0 + kt * 32 + 16);
        float4 a1 = *reinterpret_cast<const float4*>(pr1 + kt * 32);
        float4 b1 = *reinterpret_cast<const float4*>(pr1 + kt * 32 + 16);
        bf16x8 bfr[4];
#pragma unroll
        for (int nt = 0; nt < 4; ++nt)
            bfr[nt] = __builtin_bit_cast(bf16x8,
                *reinterpret_cast<const uint32x4*>(bb + nt * 16384 + kt * 512));
        float v80[8] = {a0.x, a0.y, a0.z, a0.w, b0.x, b0.y, b0.z, b0.w};
        float v81[8] = {a1.x, a1.y, a1.z, a1.w, b1.x, b1.y, b1.z, b1.w};
        uint32x4 w0, w1;
#pragma unroll
        for (int j = 0; j < 4; ++j) {
            w0[j] = (unsigned int)f2bf(v80[2 * j]) |
                    ((unsigned int)f2bf(v80[2 * j + 1]) << 16);
            w1[j] = (unsigned int)f2bf(v81[2 * j]) |
                    ((unsigned int)f2bf(v81[2 * j + 1]) << 16);
        }
        bf16x8 pfr0 = __builtin_bit_cast(bf16x8, w0);
        bf16x8 pfr1 = __builtin_bit_cast(bf16x8, w1);
#pragma unroll
        for (int nt = 0; nt < 4; ++nt) {
            q[0][nt] = __builtin_amdgcn_mfma_f32_16x16x32_bf16(pfr0, bfr[nt], q[0][nt], 0, 0, 0);
            q[1][nt] = __builtin_amdgcn_mfma_f32_16x16x32_bf16(pfr1, bfr[nt], q[1][nt], 0, 0, 0);
        }
    }

#pragma unroll
    for (int g = 0; g < 2; ++g) {
        float* qrow0 = out_q + (size_t)(row0 + g * 16 + lrow * 4) * DD + dbw + lcol;
#pragma unroll
        for (int r = 0; r < 4; ++r) {
            float* qr = qrow0 + r * DD;
#pragma unroll
            for (int nt = 0; nt < 4; ++nt) qr[nt * 16] = q[g][nt][r];
        }
    }
}

extern "C" void kernel_launch(void* const* d_in, const int* in_sizes, int n_in,
                              void* d_out, int out_size, void* d_ws, size_t ws_size,
                              hipStream_t stream) {
    (void)in_sizes; (void)n_in; (void)out_size; (void)ws_size;
    const float* x   = (const float*)d_in[0];   // [16,4096,256]
    const float* cb  = (const float*)d_in[1];   // [1024,256]
    const float* gum = (const float*)d_in[2];   // [65536,1024]

    const int N = 16 * 4096;
    float* out_q = (float*)d_out;                       // [N][256]
    float* out_p = out_q + (size_t)N * DD;              // [N][1024]

    unsigned short* cbA = (unsigned short*)d_ws;        // 576 KB fragment-major
    unsigned short* cbB = cbA + (size_t)64 * KC1 * 128; // 512 KB fragment-major
    vq_prep_kernel<<<VV, 256, 0, stream>>>(cb, cbA, cbB);
    vq_softmax_kernel<<<N / BN, 512, 0, stream>>>(x, gum, cbA, out_p);
    vq_gemm2_kernel<<<N / 32, 256, 0, stream>>>(out_p, cbB, out_q);
}

// Round 10
// 424.999 us; speedup vs baseline: 1.2213x; 1.1347x over previous
//
#include <hip/hip_runtime.h>

typedef __bf16 bf16x8 __attribute__((ext_vector_type(8)));
typedef float f32x4 __attribute__((ext_vector_type(4)));
typedef unsigned int uint32x4 __attribute__((ext_vector_type(4)));

#define DD 256
#define VV 1024
#define BN 16
#define KC1 36   // extended-K chunks of 8 (288/8): 32 data + c2 + zeros
#define WVA 8    // waves in kernel A
#define VCH 128  // V-chunk per wave in kernel A

__device__ __forceinline__ unsigned short f2bf(float f) {
    unsigned int b = __float_as_uint(f);
    b += 0x7FFFu + ((b >> 16) & 1u);
    return (unsigned short)(b >> 16);
}

// async global->LDS, 16B per lane. LDS dst must be WAVE-UNIFORM base
// (HW adds lane*16); global src is per-lane.
typedef __attribute__((address_space(3))) unsigned int lds_uint;
typedef __attribute__((address_space(1))) const unsigned int glb_uint;
__device__ __forceinline__ void dma16(const float* g, float* l) {
    __builtin_amdgcn_global_load_lds((glb_uint*)g, (lds_uint*)l, 16, 0, 0);
}

// Prep: fragment-major, sigma-permuted codebook layouts.
// sigma: element d -> kc = (d>>5)*4 + ((d>>2)&3), j = (d&3) + ((d>>4)&1)*4.
__global__ __launch_bounds__(256) void vq_prep_kernel(
    const float* __restrict__ cb,
    unsigned short* __restrict__ cbA,   // [V/16][KC1][16][8]
    unsigned short* __restrict__ cbB)   // [D/16][128][16][8]
{
    int v = blockIdx.x;
    int t = threadIdx.x;
    float val = cb[(size_t)v * DD + t];
    unsigned short h = f2bf(val);
    const int vtile = v >> 4, vi = v & 15;
    const int kc_t = (t >> 5) * 4 + ((t >> 2) & 3);
    const int j_t  = (t & 3) + ((t >> 4) & 1) * 4;
    cbA[(((size_t)vtile * KC1 + kc_t) * 16 + vi) * 8 + j_t] = h;
    const int kcv = (v >> 5) * 4 + ((v >> 2) & 3);
    const int jv  = (v & 3) + ((v >> 4) & 1) * 4;
    cbB[(((size_t)(t >> 4) * 128 + kcv) * 16 + (t & 15)) * 8 + jv] = h;

    float p = val * val;
#pragma unroll
    for (int d = 1; d < 64; d <<= 1) p += __shfl_xor(p, d);
    __shared__ float ps[4];
    if ((t & 63) == 0) ps[t >> 6] = p;
    __syncthreads();
    if (t < 32) {
        float c2 = ps[0] + ps[1] + ps[2] + ps[3];
        float m = -0.5f * c2;
        unsigned short hi = f2bf(m);
        float hif = __uint_as_float((unsigned int)hi << 16);
        unsigned short lo = f2bf(m - hif);
        unsigned short o = (t == 0) ? hi : ((t == 1) ? lo : (unsigned short)0);
        cbA[(((size_t)vtile * KC1 + 32 + (t >> 3)) * 16 + vi) * 8 + (t & 7)] = o;
    }
}

// Kernel A: GEMM1 + fused gumbel-softmax -> out_p.
// x/gumbel staged to LDS via global_load_lds; counted vmcnt keeps gumbel DMA
// in flight under GEMM1. Softmax is single-pass with NO max subtraction:
// logits are bounded (g <= 23 -> lg <= 11.5; lg >= ~-35), so exp2 with a
// fixed reference is overflow/underflow-safe in f32. acc (AGPR) read once.
__global__ __launch_bounds__(512, 4) void vq_softmax_kernel(
    const float* __restrict__ x,          // [N][D]
    const float* __restrict__ gum,        // [N][V]
    const unsigned short* __restrict__ cbA,
    float* __restrict__ out_p)            // [N][V]
{
    __shared__ __align__(16) float xbuf[BN * DD];   // 16 KB (reused for Z-reduce)
    __shared__ __align__(16) float gbuf[BN * VV];   // 64 KB

    const int tid  = threadIdx.x;
    const int wave = tid >> 6;    // 0..7
    const int lane = tid & 63;
    const int lrow = (lane >> 4) & 3;
    const int lcol = lane & 15;
    const int row0 = blockIdx.x * BN;
    const int vb   = wave * VCH;

    // ---- DMA issue: x rows (2/wave), then gumbel rows (2/wave x 4 KB) ----
    // 16B-granule XOR swizzle (both-sides involution) on the global source.
#pragma unroll
    for (int h = 0; h < 2; ++h) {
        const int r = wave * 2 + h;
        dma16(x + (size_t)(row0 + r) * DD + (((lane ^ (r & 7)) & 63) << 2),
              &xbuf[r * DD]);
    }
#pragma unroll
    for (int h = 0; h < 2; ++h) {
        const int r = wave * 2 + h;
        const float* gsrc = gum + (size_t)(row0 + r) * VV;
#pragma unroll
        for (int i = 0; i < 4; ++i) {
            const int g = i * 64 + lane;
            dma16(gsrc + ((g ^ (r & 7)) << 2), &gbuf[r * VV + i * 256]);
        }
    }
    // wait x (2 oldest of 10 per wave), leave 8 gumbel DMAs in flight
    asm volatile("s_waitcnt vmcnt(8)" ::: "memory");
    __builtin_amdgcn_sched_barrier(0);
    __builtin_amdgcn_s_barrier();

    // ---- afr from xbuf (sigma slots) + x2; native bf16 casts ----
    bf16x8 afr[9];
    float x2 = 0.f;
#pragma unroll
    for (int kt = 0; kt < 8; ++kt) {
        const int g1 = (kt * 8 + lrow) ^ (lcol & 7);
        const int g2 = (kt * 8 + lrow + 4) ^ (lcol & 7);
        f32x4 a = *reinterpret_cast<const f32x4*>(&xbuf[lcol * DD + g1 * 4]);
        f32x4 b = *reinterpret_cast<const f32x4*>(&xbuf[lcol * DD + g2 * 4]);
        bf16x8 fr;
#pragma unroll
        for (int j = 0; j < 4; ++j) {
            x2 += a[j] * a[j] + b[j] * b[j];
            fr[j]     = (__bf16)a[j];
            fr[j + 4] = (__bf16)b[j];
        }
        afr[kt] = fr;
    }
    x2 += __shfl_xor(x2, 16);
    x2 += __shfl_xor(x2, 32);   // full-row x2 of row lcol
    {
        uint32x4 w = {0u, 0u, 0u, 0u};
        if (lrow == 0) w[0] = 0x3F803F80u;  // bf16 1.0 pair at c2 slots
        afr[8] = __builtin_bit_cast(bf16x8, w);
    }

    // ---- GEMM1 (swapped): acc[nt]: v = vb+16nt+4lrow+r, x-row = lcol ----
    f32x4 acc[8];
#pragma unroll
    for (int nt = 0; nt < 8; ++nt) acc[nt] = (f32x4){0.f, 0.f, 0.f, 0.f};

    const int laneoff = lrow * 128 + lcol * 8;
#pragma unroll
    for (int nt = 0; nt < 8; ++nt) {
        const unsigned short* ap =
            cbA + ((size_t)(vb >> 4) + nt) * (KC1 * 128) + laneoff;
#pragma unroll
        for (int kt = 0; kt < 9; ++kt) {
            bf16x8 cfr = __builtin_bit_cast(bf16x8,
                *reinterpret_cast<const uint32x4*>(ap + kt * 512));
            acc[nt] = __builtin_amdgcn_mfma_f32_16x16x32_bf16(cfr, afr[kt], acc[nt], 0, 0, 0);
        }
    }

    // gumbel DMA done + all waves past xbuf reads
    asm volatile("s_waitcnt vmcnt(0)" ::: "memory");
    __builtin_amdgcn_sched_barrier(0);
    __builtin_amdgcn_s_barrier();

    // ---- gumbel from LDS (all 8 vectors up front -> deep ILP) ----
    f32x4 u4[8];
#pragma unroll
    for (int nt = 0; nt < 8; ++nt) {
        const int gg = ((vb >> 2) + nt * 4 + lrow) ^ (lcol & 7);
        u4[nt] = *reinterpret_cast<const f32x4*>(&gbuf[lcol * VV + gg * 4]);
    }

    // ---- single-pass no-max softmax ----
    // lg2 = log2(P_unnorm) = -0.5*log2(w) - 0.72134752*dist, w = -ln(u)
    float ss = 0.f;
    f32x4 pe[8];
#pragma unroll
    for (int nt = 0; nt < 8; ++nt) {
#pragma unroll
        for (int r = 0; r < 4; ++r) {
            float u = fminf(fmaxf(u4[nt][r], 1e-10f), 1.0f - 1e-10f);
            float l2u = __builtin_amdgcn_logf(u);           // log2(u)
            float t = u - 1.0f;
            float pp = t * (1.0f + t * (-0.5f + t * (0.33333333f + t * (-0.25f + t * 0.2f))));
            float w = (u >= 0.984375f) ? -pp : (l2u * -0.69314718f);
            float l2w = __builtin_amdgcn_logf(w);           // log2(w)
            float d2 = fmaxf(__builtin_fmaf(-2.0f, acc[nt][r], x2), 1e-12f);
            float dist = __builtin_amdgcn_sqrtf(d2);
            float lg2 = __builtin_fmaf(-0.72134752f, dist, -0.5f * l2w);
            float e = __builtin_amdgcn_exp2f(lg2);
            pe[nt][r] = e;
            ss += e;
        }
    }
    ss += __shfl_xor(ss, 16);
    ss += __shfl_xor(ss, 32);   // full-row sum for row lcol (this V-chunk)

    // cross-wave Z-sum via xbuf (free after GEMM1: all waves passed barrier 2)
    if (lane < 16) xbuf[wave * 16 + lane] = ss;
    asm volatile("s_waitcnt lgkmcnt(0)" ::: "memory");
    __builtin_amdgcn_s_barrier();

    float Z = 0.f;
#pragma unroll
    for (int w = 0; w < WVA; ++w) Z += xbuf[w * 16 + lcol];
    const float rinv = 1.0f / Z;

    // ---- out_p: per-lane float4 stores (exact f32, v-contiguous) ----
    {
        float* oprow = out_p + (size_t)(row0 + lcol) * VV + vb + lrow * 4;
#pragma unroll
        for (int nt = 0; nt < 8; ++nt)
            *reinterpret_cast<float4*>(oprow + nt * 16) =
                (float4){pe[nt][0] * rinv, pe[nt][1] * rinv,
                         pe[nt][2] * rinv, pe[nt][3] * rinv};
    }
}

// Kernel B: out_q = prob @ cb. 64 rows/block (4 row-groups of 16), 4 waves
// owning D-chunks of 64; cbB fragments reused across the 4 row-groups.
// Sigma-permuted prob loads; native bf16 casts for conversion.
__global__ __launch_bounds__(256, 4) void vq_gemm2_kernel(
    const float* __restrict__ out_p,      // [N][V]
    const unsigned short* __restrict__ cbB,
    float* __restrict__ out_q)            // [N][D]
{
    const int tid  = threadIdx.x;
    const int wave = tid >> 6;
    const int lane = tid & 63;
    const int lrow = (lane >> 4) & 3;
    const int lcol = lane & 15;
    const int row0 = blockIdx.x * 64;
    const int dbw  = wave * 64;
    const int laneoff = lrow * 128 + lcol * 8;

    const unsigned short* bb =
        cbB + (size_t)(dbw >> 4) * (128 * 128) + laneoff;

    f32x4 q[4][4];
#pragma unroll
    for (int g = 0; g < 4; ++g)
#pragma unroll
        for (int nt = 0; nt < 4; ++nt) q[g][nt] = (f32x4){0.f, 0.f, 0.f, 0.f};

#pragma unroll 2
    for (int kt = 0; kt < 32; ++kt) {
        bf16x8 bfr[4];
#pragma unroll
        for (int nt = 0; nt < 4; ++nt)
            bfr[nt] = __builtin_bit_cast(bf16x8,
                *reinterpret_cast<const uint32x4*>(bb + nt * 16384 + kt * 512));
#pragma unroll
        for (int g = 0; g < 4; ++g) {
            const float* pr =
                out_p + (size_t)(row0 + g * 16 + lcol) * VV + kt * 32 + lrow * 4;
            f32x4 a = *reinterpret_cast<const f32x4*>(pr);
            f32x4 b = *reinterpret_cast<const f32x4*>(pr + 16);
            bf16x8 pfr;
#pragma unroll
            for (int j = 0; j < 4; ++j) {
                pfr[j]     = (__bf16)a[j];
                pfr[j + 4] = (__bf16)b[j];
            }
#pragma unroll
            for (int nt = 0; nt < 4; ++nt)
                q[g][nt] = __builtin_amdgcn_mfma_f32_16x16x32_bf16(pfr, bfr[nt], q[g][nt], 0, 0, 0);
        }
    }

    // store: C[row = row0 + g*16 + lrow*4 + r][d = dbw + nt*16 + lcol]
#pragma unroll
    for (int g = 0; g < 4; ++g) {
        float* qrow0 = out_q + (size_t)(row0 + g * 16 + lrow * 4) * DD + dbw + lcol;
#pragma unroll
        for (int r = 0; r < 4; ++r) {
            float* qr = qrow0 + r * DD;
#pragma unroll
            for (int nt = 0; nt < 4; ++nt) qr[nt * 16] = q[g][nt][r];
        }
    }
}

extern "C" void kernel_launch(void* const* d_in, const int* in_sizes, int n_in,
                              void* d_out, int out_size, void* d_ws, size_t ws_size,
                              hipStream_t stream) {
    (void)in_sizes; (void)n_in; (void)out_size; (void)ws_size;
    const float* x   = (const float*)d_in[0];   // [16,4096,256]
    const float* cb  = (const float*)d_in[1];   // [1024,256]
    const float* gum = (const float*)d_in[2];   // [65536,1024]

    const int N = 16 * 4096;
    float* out_q = (float*)d_out;                       // [N][256]
    float* out_p = out_q + (size_t)N * DD;              // [N][1024]

    unsigned short* cbA = (unsigned short*)d_ws;        // 576 KB fragment-major
    unsigned short* cbB = cbA + (size_t)64 * KC1 * 128; // 512 KB fragment-major
    vq_prep_kernel<<<VV, 256, 0, stream>>>(cb, cbA, cbB);
    vq_softmax_kernel<<<N / BN, 512, 0, stream>>>(x, gum, cbA, out_p);
    vq_gemm2_kernel<<<N / 64, 256, 0, stream>>>(out_p, cbB, out_q);
}